// Round 1
// baseline (306.134 us; speedup 1.0000x reference)
//
#include <hip/hip_runtime.h>
#include <hip/hip_bf16.h>
#include <stdint.h>

// Problem constants (fixed by setup_inputs)
#define B_   64
#define H_   512
#define W_   512
#define S_N  1024      // n_segments
#define E_N  768       // embed_dim
#define K_N  768       // C*box*box = 3*16*16
#define HALF 8

typedef short bf16x8 __attribute__((ext_vector_type(8)));
typedef float f32x4  __attribute__((ext_vector_type(4)));

__device__ __forceinline__ unsigned short f2bf(float f) {
  union { float f; unsigned u; } v; v.f = f;
  unsigned u = v.u;
  u += 0x7FFF + ((u >> 16) & 1);   // RNE
  return (unsigned short)(u >> 16);
}

// ---------------- Phase 1: per-(b,s) integer sums of (x, y, 1) ----------------
// Exactness: partial sums are integers < 2^24, so the reference's float32
// scatter-add is exact too -> integer sums == reference sums bit-for-bit.
__global__ void k_accum(const int* __restrict__ seg, int* __restrict__ sums) {
  __shared__ int ls[S_N * 3];
  const int tid = threadIdx.x;
  const int b = blockIdx.y;
  for (int i = tid; i < S_N * 3; i += 256) ls[i] = 0;
  __syncthreads();
  const int pix0 = blockIdx.x * 16384;
  const int* segb = seg + (size_t)b * (H_ * W_);
  for (int it = 0; it < 64; ++it) {
    int p = pix0 + it * 256 + tid;
    int s = segb[p];
    s = ((unsigned)s < S_N) ? s : 0;
    int x = p & (W_ - 1);
    int y = p >> 9;
    atomicAdd(&ls[s * 3 + 0], x);
    atomicAdd(&ls[s * 3 + 1], y);
    atomicAdd(&ls[s * 3 + 2], 1);
  }
  __syncthreads();
  int* gb = sums + (size_t)b * S_N * 3;
  for (int s = tid; s < S_N; s += 256) {
    int c = ls[s * 3 + 2];
    if (c) {
      atomicAdd(&gb[s * 3 + 0], ls[s * 3 + 0]);
      atomicAdd(&gb[s * 3 + 1], ls[s * 3 + 1]);
      atomicAdd(&gb[s * 3 + 2], c);
    }
  }
}

// ---------------- Phase 2: centroid -> (x_min, y_min), IEEE f32 div + floor ----
__global__ void k_coords(const int* __restrict__ sums, int2* __restrict__ coords) {
  int m = blockIdx.x * 256 + threadIdx.x;
  int sx = sums[m * 3 + 0];
  int sy = sums[m * 3 + 1];
  int c  = sums[m * 3 + 2];
  float xc = 0.f, yc = 0.f;
  if (c > 0) {
    float cf = (float)c;
    xc = (float)sx / cf;   // IEEE f32 div of exact ints == reference
    yc = (float)sy / cf;
  }
  coords[m] = make_int2((int)floorf(xc), (int)floorf(yc));
}

// ---------------- conv_w fp32 -> bf16 (layout [E][K] already K-major) ----------
__global__ void k_convw(const float* __restrict__ w, unsigned short* __restrict__ wb) {
  int i = blockIdx.x * 256 + threadIdx.x;
  wb[i] = f2bf(w[i]);
}

// ---------------- Phase 3a: materialize patches as bf16 A[M][K] ----------------
__global__ void k_patch(const float* __restrict__ img, const int2* __restrict__ coords,
                        unsigned short* __restrict__ A) {
  int gid = blockIdx.x * 256 + threadIdx.x;   // 12,582,912 threads, 4 elems each
  int m  = gid / 192;
  int kq = (gid - m * 192) * 4;               // k..k+3 share (c,h), consecutive w
  int2 cc = coords[m];
  int b = m >> 10;
  int c = kq >> 8;
  int h = (kq >> 4) & 15;
  int w0 = kq & 15;
  int y = cc.y + h - HALF;
  bool yok = ((unsigned)y < H_);
  const float* rowp = img + (((size_t)(b * 3 + c) * H_ + (yok ? y : 0)) * W_);
  int xb = cc.x + w0 - HALF;
  float v0 = (yok && (unsigned)(xb + 0) < W_) ? rowp[xb + 0] : 0.f;
  float v1 = (yok && (unsigned)(xb + 1) < W_) ? rowp[xb + 1] : 0.f;
  float v2 = (yok && (unsigned)(xb + 2) < W_) ? rowp[xb + 2] : 0.f;
  float v3 = (yok && (unsigned)(xb + 3) < W_) ? rowp[xb + 3] : 0.f;
  ushort4 o;
  o.x = f2bf(v0); o.y = f2bf(v1); o.z = f2bf(v2); o.w = f2bf(v3);
  *(ushort4*)(A + (size_t)m * K_N + kq) = o;
}

// ---------------- Phase 3b: bf16 MFMA GEMM, C[M,N] = A[M,K] * B[N,K]^T --------
// m97-style: 128x128 tile, BK=64, 4 waves (2x2), global_load_lds width-16.
template<bool GATHER>
__global__ __launch_bounds__(256) void k_gemm(
    const unsigned short* __restrict__ Amat,
    const float* __restrict__ img,
    const int2* __restrict__ coords,
    const unsigned short* __restrict__ Bmat,
    float* __restrict__ out) {
  __shared__ unsigned short As[128 * 64];
  __shared__ unsigned short Bs[128 * 64];
  const int tid  = threadIdx.x;
  const int wave = tid >> 6;
  const int lane = tid & 63;
  const int bn = blockIdx.x;   // 0..5
  const int bm = blockIdx.y;   // 0..511
  const int wr = wave >> 1, wc = wave & 1;
  const int trow = tid >> 3;          // 0..31
  const int tcol = (tid & 7) * 8;     // short offset 0..56

  f32x4 acc[4][4];
  #pragma unroll
  for (int i = 0; i < 4; ++i)
    #pragma unroll
    for (int j = 0; j < 4; ++j)
      acc[i][j] = (f32x4){0.f, 0.f, 0.f, 0.f};

  for (int kt = 0; kt < 12; ++kt) {
    const int k0 = kt * 64;
    __syncthreads();   // previous tile's compute fully done before overwrite
    if (!GATHER) {
      #pragma unroll
      for (int i = 0; i < 4; ++i) {
        const unsigned short* g = Amat + (size_t)(bm * 128 + i * 32 + trow) * K_N + k0 + tcol;
        unsigned short* l = &As[(i * 32 + wave * 8) * 64];   // wave-uniform base
        __builtin_amdgcn_global_load_lds((const __attribute__((address_space(1))) void*)g,
                                         (__attribute__((address_space(3))) void*)l, 16, 0, 0);
      }
    } else {
      #pragma unroll
      for (int i = 0; i < 4; ++i) {
        int row = i * 32 + trow;
        int m = bm * 128 + row;
        int2 cc = coords[m];
        int b = m >> 10;
        int k = k0 + tcol;
        int c = k >> 8, h = (k >> 4) & 15, w0 = k & 15;
        int y = cc.y + h - HALF;
        bool yok = ((unsigned)y < H_);
        const float* rowp = img + (((size_t)(b * 3 + c) * H_ + (yok ? y : 0)) * W_);
        bf16x8 t;
        #pragma unroll
        for (int j = 0; j < 8; ++j) {
          int x = cc.x + w0 + j - HALF;
          float v = (yok && (unsigned)x < W_) ? rowp[x] : 0.f;
          t[j] = (short)f2bf(v);
        }
        *(bf16x8*)&As[row * 64 + tcol] = t;
      }
    }
    #pragma unroll
    for (int i = 0; i < 4; ++i) {
      const unsigned short* g = Bmat + (size_t)(bn * 128 + i * 32 + trow) * K_N + k0 + tcol;
      unsigned short* l = &Bs[(i * 32 + wave * 8) * 64];
      __builtin_amdgcn_global_load_lds((const __attribute__((address_space(1))) void*)g,
                                       (__attribute__((address_space(3))) void*)l, 16, 0, 0);
    }
    __syncthreads();   // drains vmcnt/lgkm -> LDS tiles ready

    #pragma unroll
    for (int kk = 0; kk < 2; ++kk) {
      const int krow = kk * 32 + (lane >> 4) * 8;
      bf16x8 a[4], bb[4];
      #pragma unroll
      for (int mi = 0; mi < 4; ++mi)
        a[mi] = *(const bf16x8*)&As[(wr * 64 + mi * 16 + (lane & 15)) * 64 + krow];
      #pragma unroll
      for (int ni = 0; ni < 4; ++ni)
        bb[ni] = *(const bf16x8*)&Bs[(wc * 64 + ni * 16 + (lane & 15)) * 64 + krow];
      #pragma unroll
      for (int mi = 0; mi < 4; ++mi)
        #pragma unroll
        for (int ni = 0; ni < 4; ++ni)
          acc[mi][ni] = __builtin_amdgcn_mfma_f32_16x16x32_bf16(a[mi], bb[ni], acc[mi][ni], 0, 0, 0);
    }
  }

  // C/D layout (m89): col = lane&15, row = (lane>>4)*4 + reg
  const int row0 = bm * 128 + wr * 64 + (lane >> 4) * 4;
  const int col0 = bn * 128 + wc * 64 + (lane & 15);
  #pragma unroll
  for (int mi = 0; mi < 4; ++mi)
    #pragma unroll
    for (int ni = 0; ni < 4; ++ni)
      #pragma unroll
      for (int r = 0; r < 4; ++r)
        out[(size_t)(row0 + mi * 16 + r) * E_N + (col0 + ni * 16)] = acc[mi][ni][r];
}

extern "C" void kernel_launch(void* const* d_in, const int* in_sizes, int n_in,
                              void* d_out, int out_size, void* d_ws, size_t ws_size,
                              hipStream_t stream) {
  const float* img = (const float*)d_in[0];
  const int*   seg = (const int*)d_in[1];
  const float* cw  = (const float*)d_in[2];
  float* out = (float*)d_out;
  char* ws = (char*)d_ws;

  int*            sums   = (int*)ws;                         // 786,432 B
  int2*           coords = (int2*)(ws + 786432);             // 524,288 B
  unsigned short* Bmat   = (unsigned short*)(ws + 1310720);  // 1,179,648 B
  unsigned short* Amat   = (unsigned short*)(ws + 2490368);  // 100,663,296 B
  const bool mat = ws_size >= (size_t)103153664;

  hipMemsetAsync(sums, 0, 786432, stream);
  k_accum<<<dim3(16, 64), 256, 0, stream>>>(seg, sums);
  k_coords<<<256, 256, 0, stream>>>(sums, coords);
  k_convw<<<2304, 256, 0, stream>>>(cw, Bmat);
  if (mat) {
    k_patch<<<49152, 256, 0, stream>>>(img, coords, Amat);
    k_gemm<false><<<dim3(6, 512), 256, 0, stream>>>(Amat, img, coords, Bmat, out);
  } else {
    k_gemm<true><<<dim3(6, 512), 256, 0, stream>>>(nullptr, img, coords, Bmat, out);
  }
}

// Round 2
// 277.868 us; speedup vs baseline: 1.1017x; 1.1017x over previous
//
#include <hip/hip_runtime.h>
#include <hip/hip_bf16.h>
#include <stdint.h>

// Problem constants (fixed by setup_inputs)
#define B_   64
#define H_   512
#define W_   512
#define S_N  1024      // n_segments
#define E_N  768       // embed_dim
#define K_N  768       // C*box*box = 3*16*16
#define HALF 8

typedef short bf16x8 __attribute__((ext_vector_type(8)));
typedef float f32x4  __attribute__((ext_vector_type(4)));

__device__ __forceinline__ unsigned short f2bf(float f) {
  union { float f; unsigned u; } v; v.f = f;
  unsigned u = v.u;
  u += 0x7FFF + ((u >> 16) & 1);   // RNE
  return (unsigned short)(u >> 16);
}

// ---------------- Phase 1: per-(b,s) integer sums of (x, y, 1) ----------------
// Exactness: partial sums are integers < 2^24, so the reference's float32
// scatter-add is exact too -> integer sums == reference sums bit-for-bit.
__global__ void k_accum(const int* __restrict__ seg, int* __restrict__ sums) {
  __shared__ int ls[S_N * 3];
  const int tid = threadIdx.x;
  const int b = blockIdx.y;
  for (int i = tid; i < S_N * 3; i += 256) ls[i] = 0;
  __syncthreads();
  const int pix0 = blockIdx.x * 16384;
  const int* segb = seg + (size_t)b * (H_ * W_);
  for (int it = 0; it < 64; ++it) {
    int p = pix0 + it * 256 + tid;
    int s = segb[p];
    s = ((unsigned)s < S_N) ? s : 0;
    int x = p & (W_ - 1);
    int y = p >> 9;
    atomicAdd(&ls[s * 3 + 0], x);
    atomicAdd(&ls[s * 3 + 1], y);
    atomicAdd(&ls[s * 3 + 2], 1);
  }
  __syncthreads();
  int* gb = sums + (size_t)b * S_N * 3;
  for (int s = tid; s < S_N; s += 256) {
    int c = ls[s * 3 + 2];
    if (c) {
      atomicAdd(&gb[s * 3 + 0], ls[s * 3 + 0]);
      atomicAdd(&gb[s * 3 + 1], ls[s * 3 + 1]);
      atomicAdd(&gb[s * 3 + 2], c);
    }
  }
}

// ---------------- Phase 2: centroid -> (x_min, y_min), IEEE f32 div + floor ----
__global__ void k_coords(const int* __restrict__ sums, int2* __restrict__ coords) {
  int m = blockIdx.x * 256 + threadIdx.x;
  int sx = sums[m * 3 + 0];
  int sy = sums[m * 3 + 1];
  int c  = sums[m * 3 + 2];
  float xc = 0.f, yc = 0.f;
  if (c > 0) {
    float cf = (float)c;
    xc = (float)sx / cf;   // IEEE f32 div of exact ints == reference
    yc = (float)sy / cf;
  }
  coords[m] = make_int2((int)floorf(xc), (int)floorf(yc));
}

// ---------------- conv_w fp32 -> bf16 (layout [E][K] already K-major) ----------
__global__ void k_convw(const float* __restrict__ w, unsigned short* __restrict__ wb) {
  int i = blockIdx.x * 256 + threadIdx.x;
  wb[i] = f2bf(w[i]);
}

// ---------------- Phase 3a: materialize patches as bf16 A[M][K] ----------------
__global__ void k_patch(const float* __restrict__ img, const int2* __restrict__ coords,
                        unsigned short* __restrict__ A) {
  int gid = blockIdx.x * 256 + threadIdx.x;   // 12,582,912 threads, 4 elems each
  int m  = gid / 192;
  int kq = (gid - m * 192) * 4;               // k..k+3 share (c,h), consecutive w
  int2 cc = coords[m];
  int b = m >> 10;
  int c = kq >> 8;
  int h = (kq >> 4) & 15;
  int w0 = kq & 15;
  int y = cc.y + h - HALF;
  bool yok = ((unsigned)y < H_);
  const float* rowp = img + (((size_t)(b * 3 + c) * H_ + (yok ? y : 0)) * W_);
  int xb = cc.x + w0 - HALF;
  float v0 = (yok && (unsigned)(xb + 0) < W_) ? rowp[xb + 0] : 0.f;
  float v1 = (yok && (unsigned)(xb + 1) < W_) ? rowp[xb + 1] : 0.f;
  float v2 = (yok && (unsigned)(xb + 2) < W_) ? rowp[xb + 2] : 0.f;
  float v3 = (yok && (unsigned)(xb + 3) < W_) ? rowp[xb + 3] : 0.f;
  ushort4 o;
  o.x = f2bf(v0); o.y = f2bf(v1); o.z = f2bf(v2); o.w = f2bf(v3);
  *(ushort4*)(A + (size_t)m * K_N + kq) = o;
}

// ---------------- Phase 3b: bf16 MFMA GEMM, C[M,N] = A[M,K] * B[N,K]^T --------
// 128x128 tile, BK=64, 4 waves (2x2), global_load_lds width-16.
// T2 both-sides swizzle (rule #21): LDS dest stays linear (global_load_lds
// writes base+lane*16); the 16B-chunk index within each row's 128B k-tile
// window is XOR'd with (row&7) on the GLOBAL source address, and the same
// XOR is applied on the ds_read side. -> all 32 banks uniformly loaded.
// T1: bijective XCD remap (grid 3072 = 8*384), bn fastest within an XCD's
// contiguous bm range -> A-panel L2 reuse per XCD.
template<bool GATHER>
__global__ __launch_bounds__(256) void k_gemm(
    const unsigned short* __restrict__ Amat,
    const float* __restrict__ img,
    const int2* __restrict__ coords,
    const unsigned short* __restrict__ Bmat,
    float* __restrict__ out) {
  __shared__ unsigned short As[128 * 64];
  __shared__ unsigned short Bs[128 * 64];
  const int tid  = threadIdx.x;
  const int wave = tid >> 6;
  const int lane = tid & 63;

  // XCD-aware remap: consecutive blockIdx round-robin across 8 XCDs.
  const int xcd   = blockIdx.x & 7;
  const int local = blockIdx.x >> 3;
  const int virt  = xcd * 384 + local;   // contiguous range per XCD
  const int bm = virt / 6;               // 0..511
  const int bn = virt - bm * 6;          // 0..5  (fastest -> same-bm blocks adjacent)

  const int wr = wave >> 1, wc = wave & 1;
  const int trow = tid >> 3;          // 0..31
  const int cchunk = tid & 7;         // 16B chunk this lane stages

  f32x4 acc[4][4];
  #pragma unroll
  for (int i = 0; i < 4; ++i)
    #pragma unroll
    for (int j = 0; j < 4; ++j)
      acc[i][j] = (f32x4){0.f, 0.f, 0.f, 0.f};

  // read-side swizzled chunk (shorts offset), uniform across mi/ni since
  // (row&7) == (lane&7) for all fragment rows (row = base8 + (lane&15)).
  const int rlo = lane & 15;
  const int rsel = lane & 7;

  for (int kt = 0; kt < 12; ++kt) {
    const int k0 = kt * 64;
    __syncthreads();   // previous tile's compute fully done before overwrite
    if (!GATHER) {
      #pragma unroll
      for (int i = 0; i < 4; ++i) {
        const int row = i * 32 + trow;
        const unsigned short* g = Amat + (size_t)(bm * 128 + row) * K_N + k0
                                + ((cchunk ^ (row & 7)) << 3);
        unsigned short* l = &As[(i * 32 + wave * 8) * 64];   // wave-uniform base
        __builtin_amdgcn_global_load_lds((const __attribute__((address_space(1))) void*)g,
                                         (__attribute__((address_space(3))) void*)l, 16, 0, 0);
      }
    } else {
      #pragma unroll
      for (int i = 0; i < 4; ++i) {
        int row = i * 32 + trow;
        int m = bm * 128 + row;
        int2 cc = coords[m];
        int b = m >> 10;
        int k = k0 + cchunk * 8;
        int c = k >> 8, h = (k >> 4) & 15, w0 = k & 15;
        int y = cc.y + h - HALF;
        bool yok = ((unsigned)y < H_);
        const float* rowp = img + (((size_t)(b * 3 + c) * H_ + (yok ? y : 0)) * W_);
        bf16x8 t;
        #pragma unroll
        for (int j = 0; j < 8; ++j) {
          int x = cc.x + w0 + j - HALF;
          float v = (yok && (unsigned)x < W_) ? rowp[x] : 0.f;
          t[j] = (short)f2bf(v);
        }
        *(bf16x8*)&As[row * 64 + ((cchunk ^ (row & 7)) << 3)] = t;
      }
    }
    #pragma unroll
    for (int i = 0; i < 4; ++i) {
      const int row = i * 32 + trow;
      const unsigned short* g = Bmat + (size_t)(bn * 128 + row) * K_N + k0
                              + ((cchunk ^ (row & 7)) << 3);
      unsigned short* l = &Bs[(i * 32 + wave * 8) * 64];
      __builtin_amdgcn_global_load_lds((const __attribute__((address_space(1))) void*)g,
                                       (__attribute__((address_space(3))) void*)l, 16, 0, 0);
    }
    __syncthreads();   // drains vmcnt/lgkm -> LDS tiles ready

    #pragma unroll
    for (int kk = 0; kk < 2; ++kk) {
      const int swzoff = ((kk * 4 + (lane >> 4)) ^ rsel) << 3;  // shorts
      bf16x8 a[4], bb[4];
      #pragma unroll
      for (int mi = 0; mi < 4; ++mi)
        a[mi] = *(const bf16x8*)&As[(wr * 64 + mi * 16 + rlo) * 64 + swzoff];
      #pragma unroll
      for (int ni = 0; ni < 4; ++ni)
        bb[ni] = *(const bf16x8*)&Bs[(wc * 64 + ni * 16 + rlo) * 64 + swzoff];
      #pragma unroll
      for (int mi = 0; mi < 4; ++mi)
        #pragma unroll
        for (int ni = 0; ni < 4; ++ni)
          acc[mi][ni] = __builtin_amdgcn_mfma_f32_16x16x32_bf16(a[mi], bb[ni], acc[mi][ni], 0, 0, 0);
    }
  }

  // C/D layout (m89): col = lane&15, row = (lane>>4)*4 + reg
  const int row0 = bm * 128 + wr * 64 + (lane >> 4) * 4;
  const int col0 = bn * 128 + wc * 64 + (lane & 15);
  #pragma unroll
  for (int mi = 0; mi < 4; ++mi)
    #pragma unroll
    for (int ni = 0; ni < 4; ++ni)
      #pragma unroll
      for (int r = 0; r < 4; ++r)
        out[(size_t)(row0 + mi * 16 + r) * E_N + (col0 + ni * 16)] = acc[mi][ni][r];
}

extern "C" void kernel_launch(void* const* d_in, const int* in_sizes, int n_in,
                              void* d_out, int out_size, void* d_ws, size_t ws_size,
                              hipStream_t stream) {
  const float* img = (const float*)d_in[0];
  const int*   seg = (const int*)d_in[1];
  const float* cw  = (const float*)d_in[2];
  float* out = (float*)d_out;
  char* ws = (char*)d_ws;

  int*            sums   = (int*)ws;                         // 786,432 B
  int2*           coords = (int2*)(ws + 786432);             // 524,288 B
  unsigned short* Bmat   = (unsigned short*)(ws + 1310720);  // 1,179,648 B
  unsigned short* Amat   = (unsigned short*)(ws + 2490368);  // 100,663,296 B
  const bool mat = ws_size >= (size_t)103153664;

  hipMemsetAsync(sums, 0, 786432, stream);
  k_accum<<<dim3(16, 64), 256, 0, stream>>>(seg, sums);
  k_coords<<<256, 256, 0, stream>>>(sums, coords);
  k_convw<<<2304, 256, 0, stream>>>(cw, Bmat);
  if (mat) {
    k_patch<<<49152, 256, 0, stream>>>(img, coords, Amat);
    k_gemm<false><<<3072, 256, 0, stream>>>(Amat, img, coords, Bmat, out);
  } else {
    k_gemm<true><<<3072, 256, 0, stream>>>(nullptr, img, coords, Bmat, out);
  }
}

// Round 3
// 264.857 us; speedup vs baseline: 1.1558x; 1.0491x over previous
//
#include <hip/hip_runtime.h>
#include <hip/hip_bf16.h>
#include <stdint.h>

// Problem constants (fixed by setup_inputs)
#define B_   64
#define H_   512
#define W_   512
#define S_N  1024      // n_segments
#define E_N  768       // embed_dim
#define K_N  768       // C*box*box = 3*16*16
#define HALF 8
#define NT   12        // K tiles of BK=64

typedef short bf16x8 __attribute__((ext_vector_type(8)));
typedef float f32x4  __attribute__((ext_vector_type(4)));
typedef unsigned short ushort8v __attribute__((ext_vector_type(8)));

__device__ __forceinline__ unsigned short f2bf(float f) {
  union { float f; unsigned u; } v; v.f = f;
  unsigned u = v.u;
  u += 0x7FFF + ((u >> 16) & 1);   // RNE
  return (unsigned short)(u >> 16);
}

// ---------------- Phase 1: per-(b,s) integer sums of (x, y, 1) ----------------
__global__ void k_accum(const int* __restrict__ seg, int* __restrict__ sums) {
  __shared__ int ls[S_N * 3];
  const int tid = threadIdx.x;
  const int b = blockIdx.y;
  for (int i = tid; i < S_N * 3; i += 256) ls[i] = 0;
  __syncthreads();
  const int pix0 = blockIdx.x * 16384;
  const int* segb = seg + (size_t)b * (H_ * W_);
  for (int it = 0; it < 64; ++it) {
    int p = pix0 + it * 256 + tid;
    int s = segb[p];
    s = ((unsigned)s < S_N) ? s : 0;
    int x = p & (W_ - 1);
    int y = p >> 9;
    atomicAdd(&ls[s * 3 + 0], x);
    atomicAdd(&ls[s * 3 + 1], y);
    atomicAdd(&ls[s * 3 + 2], 1);
  }
  __syncthreads();
  int* gb = sums + (size_t)b * S_N * 3;
  for (int s = tid; s < S_N; s += 256) {
    int c = ls[s * 3 + 2];
    if (c) {
      atomicAdd(&gb[s * 3 + 0], ls[s * 3 + 0]);
      atomicAdd(&gb[s * 3 + 1], ls[s * 3 + 1]);
      atomicAdd(&gb[s * 3 + 2], c);
    }
  }
}

// ---------------- Phase 2: centroid -> (x_min, y_min) ----------
__global__ void k_coords(const int* __restrict__ sums, int2* __restrict__ coords) {
  int m = blockIdx.x * 256 + threadIdx.x;
  int sx = sums[m * 3 + 0];
  int sy = sums[m * 3 + 1];
  int c  = sums[m * 3 + 2];
  float xc = 0.f, yc = 0.f;
  if (c > 0) {
    float cf = (float)c;
    xc = (float)sx / cf;
    yc = (float)sy / cf;
  }
  coords[m] = make_int2((int)floorf(xc), (int)floorf(yc));
}

// ---------------- conv_w fp32 -> bf16 ----------
__global__ void k_convw(const float* __restrict__ w, unsigned short* __restrict__ wb) {
  int i = blockIdx.x * 256 + threadIdx.x;
  wb[i] = f2bf(w[i]);
}

// ---------------- Phase 3a: materialize patches as bf16 A[M][K], 16B stores ----
__global__ void k_patch(const float* __restrict__ img, const int2* __restrict__ coords,
                        unsigned short* __restrict__ A) {
  int gid = blockIdx.x * 256 + threadIdx.x;   // 6,291,456 threads, 8 elems each
  int m  = gid / 96;
  int kq = (gid - m * 96) * 8;                // (c,h) fixed, 8 consecutive w
  int2 cc = coords[m];
  int b = m >> 10;
  int c = kq >> 8;
  int h = (kq >> 4) & 15;
  int w0 = kq & 15;                           // 0 or 8
  int y = cc.y + h - HALF;
  bool yok = ((unsigned)y < H_);
  const float* rowp = img + (((size_t)(b * 3 + c) * H_ + (yok ? y : 0)) * W_);
  int xb = cc.x + w0 - HALF;
  ushort8v o;
  #pragma unroll
  for (int j = 0; j < 8; ++j) {
    float v = (yok && (unsigned)(xb + j) < W_) ? rowp[xb + j] : 0.f;
    o[j] = f2bf(v);
  }
  *(ushort8v*)(A + (size_t)m * K_N + kq) = o;
}

// ---------------- Phase 3b: 256x256 8-phase bf16 MFMA GEMM (T1+T2+T3+T4+T5) ---
// 512 thr = 8 waves (2M x 4N); per-wave out 128x64; BK=64; LDS 128 KiB dbuf.
// Quadrant order Q(0,0),(0,1),(1,1),(1,0). One half-tile staged per phase;
// counted vmcnt(4) at phases 4 & 8 only (depth-2 half-tiles in flight).
// T2 both-sides swizzle: chunk ^= row&7 on global source, same XOR on ds_read.
__global__ __launch_bounds__(512) void k_gemm8(
    const unsigned short* __restrict__ Amat,
    const unsigned short* __restrict__ Bmat,
    float* __restrict__ out) {
  __shared__ unsigned short As[2][256 * 64];
  __shared__ unsigned short Bs[2][256 * 64];
  const int tid  = threadIdx.x;
  const int wave = tid >> 6;
  const int lane = tid & 63;

  // bijective XCD remap: 768 blocks = 8 XCDs x 96
  const int virt = (blockIdx.x & 7) * 96 + (blockIdx.x >> 3);
  const int bm = virt / 3;
  const int bn = virt - bm * 3;
  const int gm0 = bm * 256;
  const int gn0 = bn * 256;

  const int wr = wave >> 2;          // 0..1
  const int wc = wave & 3;           // 0..3
  const int rlo  = lane & 15;
  const int rsel = lane & 7;
  const int sub  = lane >> 4;        // 0..3
  int swz[2];
  swz[0] = ((0 + sub) ^ rsel) * 8;   // shorts offset, kk=0
  swz[1] = ((4 + sub) ^ rsel) * 8;   // kk=1

  // staging lane constants
  const int srow = lane >> 3;             // row within 8-row group
  const int sch  = (lane & 7) ^ srow;     // pre-swizzled source chunk

  f32x4 acc[8][4];
  #pragma unroll
  for (int i = 0; i < 8; ++i)
    #pragma unroll
    for (int j = 0; j < 4; ++j)
      acc[i][j] = (f32x4){0.f, 0.f, 0.f, 0.f};

  auto stageA = [&](int buf, int mh, int k0) {
    #pragma unroll
    for (int l = 0; l < 2; ++l) {
      int idx = wave * 2 + l;                                // 0..15
      int rowbase = mh * 64 + (idx >> 3) * 128 + (idx & 7) * 8;
      const unsigned short* g = Amat + (size_t)(gm0 + rowbase + srow) * K_N + k0 + sch * 8;
      __builtin_amdgcn_global_load_lds((const __attribute__((address_space(1))) void*)g,
        (__attribute__((address_space(3))) void*)&As[buf][rowbase * 64], 16, 0, 0);
    }
  };
  auto stageB = [&](int buf, int nh, int k0) {
    #pragma unroll
    for (int l = 0; l < 2; ++l) {
      int idx = wave * 2 + l;
      int rowbase = (idx >> 2) * 64 + nh * 32 + (idx & 3) * 8;
      const unsigned short* g = Bmat + (size_t)(gn0 + rowbase + srow) * K_N + k0 + sch * 8;
      __builtin_amdgcn_global_load_lds((const __attribute__((address_space(1))) void*)g,
        (__attribute__((address_space(3))) void*)&Bs[buf][rowbase * 64], 16, 0, 0);
    }
  };

  bf16x8 a[4][2], b[2][2];

#define LOAD_A(BUF, MH) \
  _Pragma("unroll") for (int mi = 0; mi < 4; ++mi) \
  _Pragma("unroll") for (int kk = 0; kk < 2; ++kk) \
    a[mi][kk] = *(const bf16x8*)&As[BUF][(wr * 128 + (MH) * 64 + mi * 16 + rlo) * 64 + swz[kk]];
#define LOAD_B(BUF, NH) \
  _Pragma("unroll") for (int ni = 0; ni < 2; ++ni) \
  _Pragma("unroll") for (int kk = 0; kk < 2; ++kk) \
    b[ni][kk] = *(const bf16x8*)&Bs[BUF][(wc * 64 + (NH) * 32 + ni * 16 + rlo) * 64 + swz[kk]];
#define MFMA_Q(MI0, NI0) \
  __builtin_amdgcn_s_setprio(1); \
  _Pragma("unroll") for (int mi = 0; mi < 4; ++mi) \
  _Pragma("unroll") for (int ni = 0; ni < 2; ++ni) \
  _Pragma("unroll") for (int kk = 0; kk < 2; ++kk) \
    acc[(MI0) + mi][(NI0) + ni] = __builtin_amdgcn_mfma_f32_16x16x32_bf16( \
        a[mi][kk], b[ni][kk], acc[(MI0) + mi][(NI0) + ni], 0, 0, 0); \
  __builtin_amdgcn_s_setprio(0);
#define SYNC_MFMA \
  __builtin_amdgcn_s_barrier(); \
  asm volatile("s_waitcnt lgkmcnt(0)" ::: "memory"); \
  __builtin_amdgcn_sched_barrier(0);
#define ENDPH __builtin_amdgcn_s_barrier();

  // Prologue: tile0 fully into buf0; tile1's hA0,hB1 into buf1 (staged last).
  stageA(0, 0, 0); stageA(0, 1, 0); stageB(0, 0, 0); stageB(0, 1, 0);
  stageA(1, 0, 64); stageB(1, 1, 64);
  asm volatile("s_waitcnt vmcnt(4)" ::: "memory");   // buf0 landed
  __builtin_amdgcn_s_barrier();

  for (int i = 0; i < 6; ++i) {
    const int kB = (2 * i + 1) * 64;
    const int kC = (2 * i + 2) * 64;
    const int kD = (2 * i + 3) * 64;
    const bool sC = (2 * i + 2) < NT;
    const bool sD = (2 * i + 3) < NT;
    // P1: Q1 of tile 2i (buf0)
    LOAD_A(0, 0); LOAD_B(0, 0);
    stageB(1, 0, kB);                 // buf1.hB0 <- tile 2i+1 (freed prev P8)
    SYNC_MFMA; MFMA_Q(0, 0); ENDPH;
    // P2
    LOAD_B(0, 1);
    stageA(1, 1, kB);                 // buf1.hA1 <- tile 2i+1 (freed prev P8)
    SYNC_MFMA; MFMA_Q(0, 2); ENDPH;
    // P3
    LOAD_A(0, 1);
    if (sC) stageA(0, 0, kC);         // buf0.hA0 <- tile 2i+2 (freed P2)
    SYNC_MFMA; MFMA_Q(4, 2); ENDPH;
    // P4
    LOAD_B(0, 0);
    if (sC) stageB(0, 1, kC);         // buf0.hB1 <- tile 2i+2 (freed P3)
    asm volatile("s_waitcnt vmcnt(4)" ::: "memory");  // tile 2i+1 fully landed
    SYNC_MFMA; MFMA_Q(4, 0); ENDPH;
    // P5: Q1 of tile 2i+1 (buf1)
    LOAD_A(1, 0); LOAD_B(1, 0);
    if (sC) stageB(0, 0, kC);         // buf0.hB0 (freed P4)
    SYNC_MFMA; MFMA_Q(0, 0); ENDPH;
    // P6
    LOAD_B(1, 1);
    if (sC) stageA(0, 1, kC);         // buf0.hA1 (freed P4)
    SYNC_MFMA; MFMA_Q(0, 2); ENDPH;
    // P7
    LOAD_A(1, 1);
    if (sD) stageA(1, 0, kD);         // buf1.hA0 <- tile 2i+3 (freed P6)
    SYNC_MFMA; MFMA_Q(4, 2); ENDPH;
    // P8
    LOAD_B(1, 0);
    if (sD) stageB(1, 1, kD);         // buf1.hB1 <- tile 2i+3 (freed P7)
    asm volatile("s_waitcnt vmcnt(4)" ::: "memory");  // tile 2i+2 fully landed
    SYNC_MFMA; MFMA_Q(4, 0); ENDPH;
  }

  // Epilogue: C/D layout col=lane&15, row=(lane>>4)*4+reg
  const int row0 = gm0 + wr * 128 + (lane >> 4) * 4;
  const int col0 = gn0 + wc * 64 + (lane & 15);
  #pragma unroll
  for (int mi = 0; mi < 8; ++mi)
    #pragma unroll
    for (int ni = 0; ni < 4; ++ni)
      #pragma unroll
      for (int r = 0; r < 4; ++r)
        out[(size_t)(row0 + mi * 16 + r) * E_N + (col0 + ni * 16)] = acc[mi][ni][r];
#undef LOAD_A
#undef LOAD_B
#undef MFMA_Q
#undef SYNC_MFMA
#undef ENDPH
}

// ---------------- Fallback: fused-gather 128x128 GEMM (if ws too small) -------
__global__ __launch_bounds__(256) void k_gemm_g(
    const float* __restrict__ img,
    const int2* __restrict__ coords,
    const unsigned short* __restrict__ Bmat,
    float* __restrict__ out) {
  __shared__ unsigned short As[128 * 64];
  __shared__ unsigned short Bs[128 * 64];
  const int tid  = threadIdx.x;
  const int wave = tid >> 6;
  const int lane = tid & 63;
  const int xcd   = blockIdx.x & 7;
  const int local = blockIdx.x >> 3;
  const int virt  = xcd * 384 + local;
  const int bm = virt / 6;
  const int bn = virt - bm * 6;
  const int wr = wave >> 1, wc = wave & 1;
  const int trow = tid >> 3;
  const int cchunk = tid & 7;
  f32x4 acc[4][4];
  #pragma unroll
  for (int i = 0; i < 4; ++i)
    #pragma unroll
    for (int j = 0; j < 4; ++j)
      acc[i][j] = (f32x4){0.f, 0.f, 0.f, 0.f};
  const int rlo = lane & 15;
  const int rsel = lane & 7;
  for (int kt = 0; kt < 12; ++kt) {
    const int k0 = kt * 64;
    __syncthreads();
    #pragma unroll
    for (int i = 0; i < 4; ++i) {
      int row = i * 32 + trow;
      int m = bm * 128 + row;
      int2 cc = coords[m];
      int b = m >> 10;
      int k = k0 + cchunk * 8;
      int c = k >> 8, h = (k >> 4) & 15, w0 = k & 15;
      int y = cc.y + h - HALF;
      bool yok = ((unsigned)y < H_);
      const float* rowp = img + (((size_t)(b * 3 + c) * H_ + (yok ? y : 0)) * W_);
      bf16x8 t;
      #pragma unroll
      for (int j = 0; j < 8; ++j) {
        int x = cc.x + w0 + j - HALF;
        float v = (yok && (unsigned)x < W_) ? rowp[x] : 0.f;
        t[j] = (short)f2bf(v);
      }
      *(bf16x8*)&As[row * 64 + ((cchunk ^ (row & 7)) << 3)] = t;
    }
    #pragma unroll
    for (int i = 0; i < 4; ++i) {
      const int row = i * 32 + trow;
      const unsigned short* g = Bmat + (size_t)(bn * 128 + row) * K_N + k0
                              + ((cchunk ^ (row & 7)) << 3);
      unsigned short* l = &Bs[(i * 32 + wave * 8) * 64];
      __builtin_amdgcn_global_load_lds((const __attribute__((address_space(1))) void*)g,
                                       (__attribute__((address_space(3))) void*)l, 16, 0, 0);
    }
    __syncthreads();
    #pragma unroll
    for (int kk = 0; kk < 2; ++kk) {
      const int swzoff = ((kk * 4 + (lane >> 4)) ^ rsel) << 3;
      bf16x8 a[4], bb[4];
      #pragma unroll
      for (int mi = 0; mi < 4; ++mi)
        a[mi] = *(const bf16x8*)&As[(wr * 64 + mi * 16 + rlo) * 64 + swzoff];
      #pragma unroll
      for (int ni = 0; ni < 4; ++ni)
        bb[ni] = *(const bf16x8*)&Bs[(wc * 64 + ni * 16 + rlo) * 64 + swzoff];
      #pragma unroll
      for (int mi = 0; mi < 4; ++mi)
        #pragma unroll
        for (int ni = 0; ni < 4; ++ni)
          acc[mi][ni] = __builtin_amdgcn_mfma_f32_16x16x32_bf16(a[mi], bb[ni], acc[mi][ni], 0, 0, 0);
    }
  }
  const int row0 = bm * 128 + wr * 64 + (lane >> 4) * 4;
  const int col0 = bn * 128 + wc * 64 + (lane & 15);
  #pragma unroll
  for (int mi = 0; mi < 4; ++mi)
    #pragma unroll
    for (int ni = 0; ni < 4; ++ni)
      #pragma unroll
      for (int r = 0; r < 4; ++r)
        out[(size_t)(row0 + mi * 16 + r) * E_N + (col0 + ni * 16)] = acc[mi][ni][r];
}

extern "C" void kernel_launch(void* const* d_in, const int* in_sizes, int n_in,
                              void* d_out, int out_size, void* d_ws, size_t ws_size,
                              hipStream_t stream) {
  const float* img = (const float*)d_in[0];
  const int*   seg = (const int*)d_in[1];
  const float* cw  = (const float*)d_in[2];
  float* out = (float*)d_out;
  char* ws = (char*)d_ws;

  int*            sums   = (int*)ws;                         // 786,432 B
  int2*           coords = (int2*)(ws + 786432);             // 524,288 B
  unsigned short* Bmat   = (unsigned short*)(ws + 1310720);  // 1,179,648 B
  unsigned short* Amat   = (unsigned short*)(ws + 2490368);  // 100,663,296 B
  const bool mat = ws_size >= (size_t)103153664;

  hipMemsetAsync(sums, 0, 786432, stream);
  k_accum<<<dim3(16, 64), 256, 0, stream>>>(seg, sums);
  k_coords<<<256, 256, 0, stream>>>(sums, coords);
  k_convw<<<2304, 256, 0, stream>>>(cw, Bmat);
  if (mat) {
    k_patch<<<24576, 256, 0, stream>>>(img, coords, Amat);
    k_gemm8<<<768, 512, 0, stream>>>(Amat, Bmat, out);
  } else {
    k_gemm_g<<<3072, 256, 0, stream>>>(img, coords, Bmat, out);
  }
}

// Round 4
// 262.243 us; speedup vs baseline: 1.1674x; 1.0100x over previous
//
#include <hip/hip_runtime.h>
#include <hip/hip_bf16.h>
#include <stdint.h>

// Problem constants (fixed by setup_inputs)
#define B_   64
#define H_   512
#define W_   512
#define S_N  1024      // n_segments
#define E_N  768       // embed_dim
#define K_N  768       // C*box*box = 3*16*16
#define HALF 8
#define NT   12        // K tiles of BK=64

typedef short bf16x8 __attribute__((ext_vector_type(8)));
typedef float f32x4  __attribute__((ext_vector_type(4)));
typedef unsigned short ushort8v __attribute__((ext_vector_type(8)));

__device__ __forceinline__ unsigned short f2bf(float f) {
  union { float f; unsigned u; } v; v.f = f;
  unsigned u = v.u;
  u += 0x7FFF + ((u >> 16) & 1);   // RNE
  return (unsigned short)(u >> 16);
}

// -------- Phase 0: zero sums (blocks 0..191) + conv_w fp32->bf16 (192..767) ---
// Replaces hipMemsetAsync: the graph-captured fillBufferAligned for 768 KB ran
// at 6.8 GB/s (~115 us/replay, top dispatch in round 3). This kernel does the
// same zeroing in ~2 us and folds in the k_convw conversion (one less launch).
__global__ void k_zero_convw(int* __restrict__ sums, const float* __restrict__ w,
                             unsigned short* __restrict__ wb) {
  const int bid = blockIdx.x;
  const int tid = threadIdx.x;
  if (bid < 192) {
    ((int4*)sums)[bid * 256 + tid] = make_int4(0, 0, 0, 0);
  } else {
    int idx = (bid - 192) * 256 + tid;          // 147,456 float4s
    float4 v = ((const float4*)w)[idx];
    ushort4 o;
    o.x = f2bf(v.x); o.y = f2bf(v.y); o.z = f2bf(v.z); o.w = f2bf(v.w);
    ((ushort4*)wb)[idx] = o;
  }
}

// ---------------- Phase 1: per-(b,s) integer sums of (x, y, 1) ----------------
// Exact: partial sums are integers < 2^24 -> f32 scatter-add in the reference
// is exact too -> integer sums == reference bit-for-bit.
__global__ void k_accum(const int* __restrict__ seg, int* __restrict__ sums) {
  __shared__ int ls[S_N * 3];
  const int tid = threadIdx.x;
  const int b = blockIdx.y;
  for (int i = tid; i < S_N * 3; i += 256) ls[i] = 0;
  __syncthreads();
  const int pix0 = blockIdx.x * 16384;
  const int* segb = seg + (size_t)b * (H_ * W_);
  for (int it = 0; it < 64; ++it) {
    int p = pix0 + it * 256 + tid;
    int s = segb[p];
    s = ((unsigned)s < S_N) ? s : 0;
    int x = p & (W_ - 1);
    int y = p >> 9;
    atomicAdd(&ls[s * 3 + 0], x);
    atomicAdd(&ls[s * 3 + 1], y);
    atomicAdd(&ls[s * 3 + 2], 1);
  }
  __syncthreads();
  int* gb = sums + (size_t)b * S_N * 3;
  for (int s = tid; s < S_N; s += 256) {
    int c = ls[s * 3 + 2];
    if (c) {
      atomicAdd(&gb[s * 3 + 0], ls[s * 3 + 0]);
      atomicAdd(&gb[s * 3 + 1], ls[s * 3 + 1]);
      atomicAdd(&gb[s * 3 + 2], c);
    }
  }
}

// ---------------- Phase 2: centroid -> (x_min, y_min) ----------
__global__ void k_coords(const int* __restrict__ sums, int2* __restrict__ coords) {
  int m = blockIdx.x * 256 + threadIdx.x;
  int sx = sums[m * 3 + 0];
  int sy = sums[m * 3 + 1];
  int c  = sums[m * 3 + 2];
  float xc = 0.f, yc = 0.f;
  if (c > 0) {
    float cf = (float)c;
    xc = (float)sx / cf;   // IEEE f32 div of exact ints == reference
    yc = (float)sy / cf;
  }
  coords[m] = make_int2((int)floorf(xc), (int)floorf(yc));
}

// ---------------- Phase 3a: materialize patches as bf16 A[M][K], 16B stores ----
__global__ void k_patch(const float* __restrict__ img, const int2* __restrict__ coords,
                        unsigned short* __restrict__ A) {
  int gid = blockIdx.x * 256 + threadIdx.x;   // 6,291,456 threads, 8 elems each
  int m  = gid / 96;
  int kq = (gid - m * 96) * 8;                // (c,h) fixed, 8 consecutive w
  int2 cc = coords[m];
  int b = m >> 10;
  int c = kq >> 8;
  int h = (kq >> 4) & 15;
  int w0 = kq & 15;                           // 0 or 8
  int y = cc.y + h - HALF;
  bool yok = ((unsigned)y < H_);
  const float* rowp = img + (((size_t)(b * 3 + c) * H_ + (yok ? y : 0)) * W_);
  int xb = cc.x + w0 - HALF;
  ushort8v o;
  #pragma unroll
  for (int j = 0; j < 8; ++j) {
    float v = (yok && (unsigned)(xb + j) < W_) ? rowp[xb + j] : 0.f;
    o[j] = f2bf(v);
  }
  *(ushort8v*)(A + (size_t)m * K_N + kq) = o;
}

// ---------------- Phase 3b: 256x256 8-phase bf16 MFMA GEMM (T1+T2+T3+T4+T5) ---
// 512 thr = 8 waves (2M x 4N); per-wave out 128x64; BK=64; LDS 128 KiB dbuf.
// Quadrant order Q(0,0),(0,1),(1,1),(1,0). One half-tile staged per phase;
// counted vmcnt(4) at phases 4 & 8 only (depth-2 half-tiles in flight).
// T2 both-sides swizzle: chunk ^= row&7 on global source, same XOR on ds_read.
__global__ __launch_bounds__(512) void k_gemm8(
    const unsigned short* __restrict__ Amat,
    const unsigned short* __restrict__ Bmat,
    float* __restrict__ out) {
  __shared__ unsigned short As[2][256 * 64];
  __shared__ unsigned short Bs[2][256 * 64];
  const int tid  = threadIdx.x;
  const int wave = tid >> 6;
  const int lane = tid & 63;

  // bijective XCD remap: 768 blocks = 8 XCDs x 96
  const int virt = (blockIdx.x & 7) * 96 + (blockIdx.x >> 3);
  const int bm = virt / 3;
  const int bn = virt - bm * 3;
  const int gm0 = bm * 256;
  const int gn0 = bn * 256;

  const int wr = wave >> 2;          // 0..1
  const int wc = wave & 3;           // 0..3
  const int rlo  = lane & 15;
  const int rsel = lane & 7;
  const int sub  = lane >> 4;        // 0..3
  int swz[2];
  swz[0] = ((0 + sub) ^ rsel) * 8;   // shorts offset, kk=0
  swz[1] = ((4 + sub) ^ rsel) * 8;   // kk=1

  // staging lane constants
  const int srow = lane >> 3;             // row within 8-row group
  const int sch  = (lane & 7) ^ srow;     // pre-swizzled source chunk

  f32x4 acc[8][4];
  #pragma unroll
  for (int i = 0; i < 8; ++i)
    #pragma unroll
    for (int j = 0; j < 4; ++j)
      acc[i][j] = (f32x4){0.f, 0.f, 0.f, 0.f};

  auto stageA = [&](int buf, int mh, int k0) {
    #pragma unroll
    for (int l = 0; l < 2; ++l) {
      int idx = wave * 2 + l;                                // 0..15
      int rowbase = mh * 64 + (idx >> 3) * 128 + (idx & 7) * 8;
      const unsigned short* g = Amat + (size_t)(gm0 + rowbase + srow) * K_N + k0 + sch * 8;
      __builtin_amdgcn_global_load_lds((const __attribute__((address_space(1))) void*)g,
        (__attribute__((address_space(3))) void*)&As[buf][rowbase * 64], 16, 0, 0);
    }
  };
  auto stageB = [&](int buf, int nh, int k0) {
    #pragma unroll
    for (int l = 0; l < 2; ++l) {
      int idx = wave * 2 + l;
      int rowbase = (idx >> 2) * 64 + nh * 32 + (idx & 3) * 8;
      const unsigned short* g = Bmat + (size_t)(gn0 + rowbase + srow) * K_N + k0 + sch * 8;
      __builtin_amdgcn_global_load_lds((const __attribute__((address_space(1))) void*)g,
        (__attribute__((address_space(3))) void*)&Bs[buf][rowbase * 64], 16, 0, 0);
    }
  };

  bf16x8 a[4][2], b[2][2];

#define LOAD_A(BUF, MH) \
  _Pragma("unroll") for (int mi = 0; mi < 4; ++mi) \
  _Pragma("unroll") for (int kk = 0; kk < 2; ++kk) \
    a[mi][kk] = *(const bf16x8*)&As[BUF][(wr * 128 + (MH) * 64 + mi * 16 + rlo) * 64 + swz[kk]];
#define LOAD_B(BUF, NH) \
  _Pragma("unroll") for (int ni = 0; ni < 2; ++ni) \
  _Pragma("unroll") for (int kk = 0; kk < 2; ++kk) \
    b[ni][kk] = *(const bf16x8*)&Bs[BUF][(wc * 64 + (NH) * 32 + ni * 16 + rlo) * 64 + swz[kk]];
#define MFMA_Q(MI0, NI0) \
  __builtin_amdgcn_s_setprio(1); \
  _Pragma("unroll") for (int mi = 0; mi < 4; ++mi) \
  _Pragma("unroll") for (int ni = 0; ni < 2; ++ni) \
  _Pragma("unroll") for (int kk = 0; kk < 2; ++kk) \
    acc[(MI0) + mi][(NI0) + ni] = __builtin_amdgcn_mfma_f32_16x16x32_bf16( \
        a[mi][kk], b[ni][kk], acc[(MI0) + mi][(NI0) + ni], 0, 0, 0); \
  __builtin_amdgcn_s_setprio(0);
#define SYNC_MFMA \
  __builtin_amdgcn_s_barrier(); \
  asm volatile("s_waitcnt lgkmcnt(0)" ::: "memory"); \
  __builtin_amdgcn_sched_barrier(0);
#define ENDPH __builtin_amdgcn_s_barrier();

  // Prologue: tile0 fully into buf0; tile1's hA0,hB1 into buf1 (staged last).
  stageA(0, 0, 0); stageA(0, 1, 0); stageB(0, 0, 0); stageB(0, 1, 0);
  stageA(1, 0, 64); stageB(1, 1, 64);
  asm volatile("s_waitcnt vmcnt(4)" ::: "memory");   // buf0 landed
  __builtin_amdgcn_s_barrier();

  for (int i = 0; i < 6; ++i) {
    const int kB = (2 * i + 1) * 64;
    const int kC = (2 * i + 2) * 64;
    const int kD = (2 * i + 3) * 64;
    const bool sC = (2 * i + 2) < NT;
    const bool sD = (2 * i + 3) < NT;
    // P1: Q1 of tile 2i (buf0)
    LOAD_A(0, 0); LOAD_B(0, 0);
    stageB(1, 0, kB);                 // buf1.hB0 <- tile 2i+1 (freed prev P8)
    SYNC_MFMA; MFMA_Q(0, 0); ENDPH;
    // P2
    LOAD_B(0, 1);
    stageA(1, 1, kB);                 // buf1.hA1 <- tile 2i+1 (freed prev P8)
    SYNC_MFMA; MFMA_Q(0, 2); ENDPH;
    // P3
    LOAD_A(0, 1);
    if (sC) stageA(0, 0, kC);         // buf0.hA0 <- tile 2i+2 (freed P2)
    SYNC_MFMA; MFMA_Q(4, 2); ENDPH;
    // P4
    LOAD_B(0, 0);
    if (sC) stageB(0, 1, kC);         // buf0.hB1 <- tile 2i+2 (freed P3)
    asm volatile("s_waitcnt vmcnt(4)" ::: "memory");  // tile 2i+1 fully landed
    SYNC_MFMA; MFMA_Q(4, 0); ENDPH;
    // P5: Q1 of tile 2i+1 (buf1)
    LOAD_A(1, 0); LOAD_B(1, 0);
    if (sC) stageB(0, 0, kC);         // buf0.hB0 (freed P4)
    SYNC_MFMA; MFMA_Q(0, 0); ENDPH;
    // P6
    LOAD_B(1, 1);
    if (sC) stageA(0, 1, kC);         // buf0.hA1 (freed P4)
    SYNC_MFMA; MFMA_Q(0, 2); ENDPH;
    // P7
    LOAD_A(1, 1);
    if (sD) stageA(1, 0, kD);         // buf1.hA0 <- tile 2i+3 (freed P6)
    SYNC_MFMA; MFMA_Q(4, 2); ENDPH;
    // P8
    LOAD_B(1, 0);
    if (sD) stageB(1, 1, kD);         // buf1.hB1 <- tile 2i+3 (freed P7)
    asm volatile("s_waitcnt vmcnt(4)" ::: "memory");  // tile 2i+2 fully landed
    SYNC_MFMA; MFMA_Q(4, 0); ENDPH;
  }

  // Epilogue: C/D layout col=lane&15, row=(lane>>4)*4+reg
  const int row0 = gm0 + wr * 128 + (lane >> 4) * 4;
  const int col0 = gn0 + wc * 64 + (lane & 15);
  #pragma unroll
  for (int mi = 0; mi < 8; ++mi)
    #pragma unroll
    for (int ni = 0; ni < 4; ++ni)
      #pragma unroll
      for (int r = 0; r < 4; ++r)
        out[(size_t)(row0 + mi * 16 + r) * E_N + (col0 + ni * 16)] = acc[mi][ni][r];
#undef LOAD_A
#undef LOAD_B
#undef MFMA_Q
#undef SYNC_MFMA
#undef ENDPH
}

// ---------------- Fallback: fused-gather 128x128 GEMM (if ws too small) -------
__global__ __launch_bounds__(256) void k_gemm_g(
    const float* __restrict__ img,
    const int2* __restrict__ coords,
    const unsigned short* __restrict__ Bmat,
    float* __restrict__ out) {
  __shared__ unsigned short As[128 * 64];
  __shared__ unsigned short Bs[128 * 64];
  const int tid  = threadIdx.x;
  const int wave = tid >> 6;
  const int lane = tid & 63;
  const int xcd   = blockIdx.x & 7;
  const int local = blockIdx.x >> 3;
  const int virt  = xcd * 384 + local;
  const int bm = virt / 6;
  const int bn = virt - bm * 6;
  const int wr = wave >> 1, wc = wave & 1;
  const int trow = tid >> 3;
  const int cchunk = tid & 7;
  f32x4 acc[4][4];
  #pragma unroll
  for (int i = 0; i < 4; ++i)
    #pragma unroll
    for (int j = 0; j < 4; ++j)
      acc[i][j] = (f32x4){0.f, 0.f, 0.f, 0.f};
  const int rlo = lane & 15;
  const int rsel = lane & 7;
  for (int kt = 0; kt < 12; ++kt) {
    const int k0 = kt * 64;
    __syncthreads();
    #pragma unroll
    for (int i = 0; i < 4; ++i) {
      int row = i * 32 + trow;
      int m = bm * 128 + row;
      int2 cc = coords[m];
      int b = m >> 10;
      int k = k0 + cchunk * 8;
      int c = k >> 8, h = (k >> 4) & 15, w0 = k & 15;
      int y = cc.y + h - HALF;
      bool yok = ((unsigned)y < H_);
      const float* rowp = img + (((size_t)(b * 3 + c) * H_ + (yok ? y : 0)) * W_);
      bf16x8 t;
      #pragma unroll
      for (int j = 0; j < 8; ++j) {
        int x = cc.x + w0 + j - HALF;
        float v = (yok && (unsigned)x < W_) ? rowp[x] : 0.f;
        t[j] = (short)f2bf(v);
      }
      *(bf16x8*)&As[row * 64 + ((cchunk ^ (row & 7)) << 3)] = t;
    }
    #pragma unroll
    for (int i = 0; i < 4; ++i) {
      const int row = i * 32 + trow;
      const unsigned short* g = Bmat + (size_t)(bn * 128 + row) * K_N + k0
                              + ((cchunk ^ (row & 7)) << 3);
      unsigned short* l = &Bs[(i * 32 + wave * 8) * 64];
      __builtin_amdgcn_global_load_lds((const __attribute__((address_space(1))) void*)g,
                                       (__attribute__((address_space(3))) void*)l, 16, 0, 0);
    }
    __syncthreads();
    #pragma unroll
    for (int kk = 0; kk < 2; ++kk) {
      const int swzoff = ((kk * 4 + (lane >> 4)) ^ rsel) << 3;
      bf16x8 a[4], bb[4];
      #pragma unroll
      for (int mi = 0; mi < 4; ++mi)
        a[mi] = *(const bf16x8*)&As[(wr * 64 + mi * 16 + rlo) * 64 + swzoff];
      #pragma unroll
      for (int ni = 0; ni < 4; ++ni)
        bb[ni] = *(const bf16x8*)&Bs[(wc * 64 + ni * 16 + rlo) * 64 + swzoff];
      #pragma unroll
      for (int mi = 0; mi < 4; ++mi)
        #pragma unroll
        for (int ni = 0; ni < 4; ++ni)
          acc[mi][ni] = __builtin_amdgcn_mfma_f32_16x16x32_bf16(a[mi], bb[ni], acc[mi][ni], 0, 0, 0);
    }
  }
  const int row0 = bm * 128 + wr * 64 + (lane >> 4) * 4;
  const int col0 = bn * 128 + wc * 64 + (lane & 15);
  #pragma unroll
  for (int mi = 0; mi < 4; ++mi)
    #pragma unroll
    for (int ni = 0; ni < 4; ++ni)
      #pragma unroll
      for (int r = 0; r < 4; ++r)
        out[(size_t)(row0 + mi * 16 + r) * E_N + (col0 + ni * 16)] = acc[mi][ni][r];
}

extern "C" void kernel_launch(void* const* d_in, const int* in_sizes, int n_in,
                              void* d_out, int out_size, void* d_ws, size_t ws_size,
                              hipStream_t stream) {
  const float* img = (const float*)d_in[0];
  const int*   seg = (const int*)d_in[1];
  const float* cw  = (const float*)d_in[2];
  float* out = (float*)d_out;
  char* ws = (char*)d_ws;

  int*            sums   = (int*)ws;                         // 786,432 B
  int2*           coords = (int2*)(ws + 786432);             // 524,288 B
  unsigned short* Bmat   = (unsigned short*)(ws + 1310720);  // 1,179,648 B
  unsigned short* Amat   = (unsigned short*)(ws + 2490368);  // 100,663,296 B
  const bool mat = ws_size >= (size_t)103153664;

  k_zero_convw<<<768, 256, 0, stream>>>(sums, cw, Bmat);   // zero + convw fused
  k_accum<<<dim3(16, 64), 256, 0, stream>>>(seg, sums);
  k_coords<<<256, 256, 0, stream>>>(sums, coords);
  if (mat) {
    k_patch<<<24576, 256, 0, stream>>>(img, coords, Amat);
    k_gemm8<<<768, 512, 0, stream>>>(Amat, Bmat, out);
  } else {
    k_gemm_g<<<3072, 256, 0, stream>>>(img, coords, Bmat, out);
  }
}

// Round 5
// 227.620 us; speedup vs baseline: 1.3449x; 1.1521x over previous
//
#include <hip/hip_runtime.h>
#include <hip/hip_bf16.h>
#include <stdint.h>

// Problem constants (fixed by setup_inputs)
#define B_   64
#define H_   512
#define W_   512
#define S_N  1024      // n_segments
#define E_N  768       // embed_dim
#define K_N  768       // C*box*box = 3*16*16
#define HALF 8
#define NT   12        // K tiles of BK=64

typedef short bf16x8 __attribute__((ext_vector_type(8)));
typedef float f32x4  __attribute__((ext_vector_type(4)));
typedef unsigned short ushort8v __attribute__((ext_vector_type(8)));

__device__ __forceinline__ unsigned short f2bf(float f) {
  union { float f; unsigned u; } v; v.f = f;
  unsigned u = v.u;
  u += 0x7FFF + ((u >> 16) & 1);   // RNE
  return (unsigned short)(u >> 16);
}

// ---------------- conv_w fp32 -> bf16, float4 loads ----------
__global__ void k_convw(const float* __restrict__ w, unsigned short* __restrict__ wb) {
  int idx = blockIdx.x * 256 + threadIdx.x;   // 147,456 float4s
  float4 v = ((const float4*)w)[idx];
  ushort4 o;
  o.x = f2bf(v.x); o.y = f2bf(v.y); o.z = f2bf(v.z); o.w = f2bf(v.w);
  ((ushort4*)wb)[idx] = o;
}

// ---------------- Phase 1: per-(b,s) packed sums, NO global atomics -----------
// Pack per-block partial (y_sum, x_sum, count) into one u64:
//   [y:24 bits @39 | x:24 bits @15 | cnt:15 bits @0]
// Per-block maxima: cnt <= 16384 (fits 15b), x_sum <= 16384*511 = 8.37M (24b),
// y_sum same -> no cross-field carries. One ds_add_u64/pixel (was 3 ds_add_u32),
// and partials are WRITTEN coalesced (was 3.1M contended global atomics).
// Exactness: integer sums; global (b,s) totals identical to reference's f32
// scatter-add (all < 2^24 with this data distribution).
__global__ void k_accum2(const int* __restrict__ seg,
                         unsigned long long* __restrict__ partials) {
  __shared__ unsigned long long ls[S_N];
  const int tid = threadIdx.x;
  const int xblk = blockIdx.x;   // 0..15
  const int b = blockIdx.y;
  for (int i = tid; i < S_N; i += 256) ls[i] = 0ULL;
  __syncthreads();
  const int pix0 = xblk * 16384;
  const int4* segb = (const int4*)(seg + (size_t)b * (H_ * W_) + pix0);
  for (int it = 0; it < 16; ++it) {
    int4 s4 = segb[it * 256 + tid];
    int p = pix0 + (it * 256 + tid) * 4;
    #pragma unroll
    for (int j = 0; j < 4; ++j) {
      int s = (&s4.x)[j];
      s = ((unsigned)s < S_N) ? s : 0;
      unsigned long long x = (unsigned)((p + j) & (W_ - 1));
      unsigned long long y = (unsigned)((p + j) >> 9);
      atomicAdd(&ls[s], (y << 39) | (x << 15) | 1ULL);
    }
  }
  __syncthreads();
  unsigned long long* gp = partials + ((size_t)b * 16 + xblk) * S_N;
  for (int s = tid; s < S_N; s += 256) gp[s] = ls[s];
}

// ---------------- Phase 2: reduce 16 partials, centroid -> (x_min, y_min) -----
__global__ void k_coords2(const unsigned long long* __restrict__ partials,
                          int2* __restrict__ coords) {
  int m = blockIdx.x * 256 + threadIdx.x;   // 65536 = B*S
  int b = m >> 10, s = m & (S_N - 1);
  unsigned sx = 0, sy = 0, c = 0;
  #pragma unroll
  for (int x = 0; x < 16; ++x) {
    unsigned long long v = partials[((size_t)b * 16 + x) * S_N + s];
    c  += (unsigned)(v & 0x7FFFULL);
    sx += (unsigned)((v >> 15) & 0xFFFFFFULL);
    sy += (unsigned)(v >> 39);
  }
  float xc = 0.f, yc = 0.f;
  if (c > 0) {
    float cf = (float)c;
    xc = (float)sx / cf;   // IEEE f32 div of exact ints == reference
    yc = (float)sy / cf;
  }
  coords[m] = make_int2((int)floorf(xc), (int)floorf(yc));
}

// ---------------- Phase 3a: materialize patches as bf16 A[M][K], 16B stores ----
__global__ void k_patch(const float* __restrict__ img, const int2* __restrict__ coords,
                        unsigned short* __restrict__ A) {
  int gid = blockIdx.x * 256 + threadIdx.x;   // 6,291,456 threads, 8 elems each
  int m  = gid / 96;
  int kq = (gid - m * 96) * 8;                // (c,h) fixed, 8 consecutive w
  int2 cc = coords[m];
  int b = m >> 10;
  int c = kq >> 8;
  int h = (kq >> 4) & 15;
  int w0 = kq & 15;                           // 0 or 8
  int y = cc.y + h - HALF;
  bool yok = ((unsigned)y < H_);
  const float* rowp = img + (((size_t)(b * 3 + c) * H_ + (yok ? y : 0)) * W_);
  int xb = cc.x + w0 - HALF;
  ushort8v o;
  #pragma unroll
  for (int j = 0; j < 8; ++j) {
    float v = (yok && (unsigned)(xb + j) < W_) ? rowp[xb + j] : 0.f;
    o[j] = f2bf(v);
  }
  *(ushort8v*)(A + (size_t)m * K_N + kq) = o;
}

// ---------------- Phase 3b: 256x256 8-phase bf16 MFMA GEMM (T1+T2+T3+T4+T5) ---
__global__ __launch_bounds__(512) void k_gemm8(
    const unsigned short* __restrict__ Amat,
    const unsigned short* __restrict__ Bmat,
    float* __restrict__ out) {
  __shared__ unsigned short As[2][256 * 64];
  __shared__ unsigned short Bs[2][256 * 64];
  const int tid  = threadIdx.x;
  const int wave = tid >> 6;
  const int lane = tid & 63;

  // bijective XCD remap: 768 blocks = 8 XCDs x 96
  const int virt = (blockIdx.x & 7) * 96 + (blockIdx.x >> 3);
  const int bm = virt / 3;
  const int bn = virt - bm * 3;
  const int gm0 = bm * 256;
  const int gn0 = bn * 256;

  const int wr = wave >> 2;          // 0..1
  const int wc = wave & 3;           // 0..3
  const int rlo  = lane & 15;
  const int rsel = lane & 7;
  const int sub  = lane >> 4;        // 0..3
  int swz[2];
  swz[0] = ((0 + sub) ^ rsel) * 8;   // shorts offset, kk=0
  swz[1] = ((4 + sub) ^ rsel) * 8;   // kk=1

  const int srow = lane >> 3;             // row within 8-row group
  const int sch  = (lane & 7) ^ srow;     // pre-swizzled source chunk

  f32x4 acc[8][4];
  #pragma unroll
  for (int i = 0; i < 8; ++i)
    #pragma unroll
    for (int j = 0; j < 4; ++j)
      acc[i][j] = (f32x4){0.f, 0.f, 0.f, 0.f};

  auto stageA = [&](int buf, int mh, int k0) {
    #pragma unroll
    for (int l = 0; l < 2; ++l) {
      int idx = wave * 2 + l;                                // 0..15
      int rowbase = mh * 64 + (idx >> 3) * 128 + (idx & 7) * 8;
      const unsigned short* g = Amat + (size_t)(gm0 + rowbase + srow) * K_N + k0 + sch * 8;
      __builtin_amdgcn_global_load_lds((const __attribute__((address_space(1))) void*)g,
        (__attribute__((address_space(3))) void*)&As[buf][rowbase * 64], 16, 0, 0);
    }
  };
  auto stageB = [&](int buf, int nh, int k0) {
    #pragma unroll
    for (int l = 0; l < 2; ++l) {
      int idx = wave * 2 + l;
      int rowbase = (idx >> 2) * 64 + nh * 32 + (idx & 3) * 8;
      const unsigned short* g = Bmat + (size_t)(gn0 + rowbase + srow) * K_N + k0 + sch * 8;
      __builtin_amdgcn_global_load_lds((const __attribute__((address_space(1))) void*)g,
        (__attribute__((address_space(3))) void*)&Bs[buf][rowbase * 64], 16, 0, 0);
    }
  };

  bf16x8 a[4][2], b[2][2];

#define LOAD_A(BUF, MH) \
  _Pragma("unroll") for (int mi = 0; mi < 4; ++mi) \
  _Pragma("unroll") for (int kk = 0; kk < 2; ++kk) \
    a[mi][kk] = *(const bf16x8*)&As[BUF][(wr * 128 + (MH) * 64 + mi * 16 + rlo) * 64 + swz[kk]];
#define LOAD_B(BUF, NH) \
  _Pragma("unroll") for (int ni = 0; ni < 2; ++ni) \
  _Pragma("unroll") for (int kk = 0; kk < 2; ++kk) \
    b[ni][kk] = *(const bf16x8*)&Bs[BUF][(wc * 64 + (NH) * 32 + ni * 16 + rlo) * 64 + swz[kk]];
#define MFMA_Q(MI0, NI0) \
  __builtin_amdgcn_s_setprio(1); \
  _Pragma("unroll") for (int mi = 0; mi < 4; ++mi) \
  _Pragma("unroll") for (int ni = 0; ni < 2; ++ni) \
  _Pragma("unroll") for (int kk = 0; kk < 2; ++kk) \
    acc[(MI0) + mi][(NI0) + ni] = __builtin_amdgcn_mfma_f32_16x16x32_bf16( \
        a[mi][kk], b[ni][kk], acc[(MI0) + mi][(NI0) + ni], 0, 0, 0); \
  __builtin_amdgcn_s_setprio(0);
#define SYNC_MFMA \
  __builtin_amdgcn_s_barrier(); \
  asm volatile("s_waitcnt lgkmcnt(0)" ::: "memory"); \
  __builtin_amdgcn_sched_barrier(0);
#define ENDPH __builtin_amdgcn_s_barrier();

  // Prologue: tile0 fully into buf0; tile1's hA0,hB1 into buf1 (staged last).
  stageA(0, 0, 0); stageA(0, 1, 0); stageB(0, 0, 0); stageB(0, 1, 0);
  stageA(1, 0, 64); stageB(1, 1, 64);
  asm volatile("s_waitcnt vmcnt(4)" ::: "memory");   // buf0 landed
  __builtin_amdgcn_s_barrier();

  for (int i = 0; i < 6; ++i) {
    const int kB = (2 * i + 1) * 64;
    const int kC = (2 * i + 2) * 64;
    const int kD = (2 * i + 3) * 64;
    const bool sC = (2 * i + 2) < NT;
    const bool sD = (2 * i + 3) < NT;
    // P1: Q1 of tile 2i (buf0)
    LOAD_A(0, 0); LOAD_B(0, 0);
    stageB(1, 0, kB);                 // buf1.hB0 <- tile 2i+1 (freed prev P8)
    SYNC_MFMA; MFMA_Q(0, 0); ENDPH;
    // P2
    LOAD_B(0, 1);
    stageA(1, 1, kB);                 // buf1.hA1 <- tile 2i+1 (freed prev P8)
    SYNC_MFMA; MFMA_Q(0, 2); ENDPH;
    // P3
    LOAD_A(0, 1);
    if (sC) stageA(0, 0, kC);         // buf0.hA0 <- tile 2i+2 (freed P2)
    SYNC_MFMA; MFMA_Q(4, 2); ENDPH;
    // P4
    LOAD_B(0, 0);
    if (sC) stageB(0, 1, kC);         // buf0.hB1 <- tile 2i+2 (freed P3)
    asm volatile("s_waitcnt vmcnt(4)" ::: "memory");  // tile 2i+1 fully landed
    SYNC_MFMA; MFMA_Q(4, 0); ENDPH;
    // P5: Q1 of tile 2i+1 (buf1)
    LOAD_A(1, 0); LOAD_B(1, 0);
    if (sC) stageB(0, 0, kC);         // buf0.hB0 (freed P4)
    SYNC_MFMA; MFMA_Q(0, 0); ENDPH;
    // P6
    LOAD_B(1, 1);
    if (sC) stageA(0, 1, kC);         // buf0.hA1 (freed P4)
    SYNC_MFMA; MFMA_Q(0, 2); ENDPH;
    // P7
    LOAD_A(1, 1);
    if (sD) stageA(1, 0, kD);         // buf1.hA0 <- tile 2i+3 (freed P6)
    SYNC_MFMA; MFMA_Q(4, 2); ENDPH;
    // P8
    LOAD_B(1, 0);
    if (sD) stageB(1, 1, kD);         // buf1.hB1 <- tile 2i+3 (freed P7)
    asm volatile("s_waitcnt vmcnt(4)" ::: "memory");  // tile 2i+2 fully landed
    SYNC_MFMA; MFMA_Q(4, 0); ENDPH;
  }

  // Epilogue: C/D layout col=lane&15, row=(lane>>4)*4+reg
  const int row0 = gm0 + wr * 128 + (lane >> 4) * 4;
  const int col0 = gn0 + wc * 64 + (lane & 15);
  #pragma unroll
  for (int mi = 0; mi < 8; ++mi)
    #pragma unroll
    for (int ni = 0; ni < 4; ++ni)
      #pragma unroll
      for (int r = 0; r < 4; ++r)
        out[(size_t)(row0 + mi * 16 + r) * E_N + (col0 + ni * 16)] = acc[mi][ni][r];
#undef LOAD_A
#undef LOAD_B
#undef MFMA_Q
#undef SYNC_MFMA
#undef ENDPH
}

// ---------------- Fallback: fused-gather 128x128 GEMM (if ws too small) -------
__global__ __launch_bounds__(256) void k_gemm_g(
    const float* __restrict__ img,
    const int2* __restrict__ coords,
    const unsigned short* __restrict__ Bmat,
    float* __restrict__ out) {
  __shared__ unsigned short As[128 * 64];
  __shared__ unsigned short Bs[128 * 64];
  const int tid  = threadIdx.x;
  const int wave = tid >> 6;
  const int lane = tid & 63;
  const int xcd   = blockIdx.x & 7;
  const int local = blockIdx.x >> 3;
  const int virt  = xcd * 384 + local;
  const int bm = virt / 6;
  const int bn = virt - bm * 6;
  const int wr = wave >> 1, wc = wave & 1;
  const int trow = tid >> 3;
  const int cchunk = tid & 7;
  f32x4 acc[4][4];
  #pragma unroll
  for (int i = 0; i < 4; ++i)
    #pragma unroll
    for (int j = 0; j < 4; ++j)
      acc[i][j] = (f32x4){0.f, 0.f, 0.f, 0.f};
  const int rlo = lane & 15;
  const int rsel = lane & 7;
  for (int kt = 0; kt < 12; ++kt) {
    const int k0 = kt * 64;
    __syncthreads();
    #pragma unroll
    for (int i = 0; i < 4; ++i) {
      int row = i * 32 + trow;
      int m = bm * 128 + row;
      int2 cc = coords[m];
      int b = m >> 10;
      int k = k0 + cchunk * 8;
      int c = k >> 8, h = (k >> 4) & 15, w0 = k & 15;
      int y = cc.y + h - HALF;
      bool yok = ((unsigned)y < H_);
      const float* rowp = img + (((size_t)(b * 3 + c) * H_ + (yok ? y : 0)) * W_);
      bf16x8 t;
      #pragma unroll
      for (int j = 0; j < 8; ++j) {
        int x = cc.x + w0 + j - HALF;
        float v = (yok && (unsigned)x < W_) ? rowp[x] : 0.f;
        t[j] = (short)f2bf(v);
      }
      *(bf16x8*)&As[row * 64 + ((cchunk ^ (row & 7)) << 3)] = t;
    }
    #pragma unroll
    for (int i = 0; i < 4; ++i) {
      const int row = i * 32 + trow;
      const unsigned short* g = Bmat + (size_t)(bn * 128 + row) * K_N + k0
                              + ((cchunk ^ (row & 7)) << 3);
      unsigned short* l = &Bs[(i * 32 + wave * 8) * 64];
      __builtin_amdgcn_global_load_lds((const __attribute__((address_space(1))) void*)g,
                                       (__attribute__((address_space(3))) void*)l, 16, 0, 0);
    }
    __syncthreads();
    #pragma unroll
    for (int kk = 0; kk < 2; ++kk) {
      const int swzoff = ((kk * 4 + (lane >> 4)) ^ rsel) << 3;
      bf16x8 a[4], bb[4];
      #pragma unroll
      for (int mi = 0; mi < 4; ++mi)
        a[mi] = *(const bf16x8*)&As[(wr * 64 + mi * 16 + rlo) * 64 + swzoff];
      #pragma unroll
      for (int ni = 0; ni < 4; ++ni)
        bb[ni] = *(const bf16x8*)&Bs[(wc * 64 + ni * 16 + rlo) * 64 + swzoff];
      #pragma unroll
      for (int mi = 0; mi < 4; ++mi)
        #pragma unroll
        for (int ni = 0; ni < 4; ++ni)
          acc[mi][ni] = __builtin_amdgcn_mfma_f32_16x16x32_bf16(a[mi], bb[ni], acc[mi][ni], 0, 0, 0);
    }
  }
  const int row0 = bm * 128 + wr * 64 + (lane >> 4) * 4;
  const int col0 = bn * 128 + wc * 64 + (lane & 15);
  #pragma unroll
  for (int mi = 0; mi < 4; ++mi)
    #pragma unroll
    for (int ni = 0; ni < 4; ++ni)
      #pragma unroll
      for (int r = 0; r < 4; ++r)
        out[(size_t)(row0 + mi * 16 + r) * E_N + (col0 + ni * 16)] = acc[mi][ni][r];
}

extern "C" void kernel_launch(void* const* d_in, const int* in_sizes, int n_in,
                              void* d_out, int out_size, void* d_ws, size_t ws_size,
                              hipStream_t stream) {
  const float* img = (const float*)d_in[0];
  const int*   seg = (const int*)d_in[1];
  const float* cw  = (const float*)d_in[2];
  float* out = (float*)d_out;
  char* ws = (char*)d_ws;

  unsigned long long* partials = (unsigned long long*)ws;    // 8,388,608 B
  int2*           coords = (int2*)(ws + 8388608);            //   524,288 B
  unsigned short* Bmat   = (unsigned short*)(ws + 8912896);  // 1,179,648 B
  unsigned short* Amat   = (unsigned short*)(ws + 10092544); // 100,663,296 B
  const bool mat = ws_size >= (size_t)110755840;

  k_convw<<<576, 256, 0, stream>>>(cw, Bmat);
  k_accum2<<<dim3(16, 64), 256, 0, stream>>>(seg, partials);
  k_coords2<<<256, 256, 0, stream>>>(partials, coords);
  if (mat) {
    k_patch<<<24576, 256, 0, stream>>>(img, coords, Amat);
    k_gemm8<<<768, 512, 0, stream>>>(Amat, Bmat, out);
  } else {
    k_gemm_g<<<3072, 256, 0, stream>>>(img, coords, Bmat, out);
  }
}